// Round 6
// baseline (178.834 us; speedup 1.0000x reference)
//
#include <hip/hip_runtime.h>

#define BB 64
#define RR 100
#define CC 2048
#define HH 512

#define S_ELEMS ((size_t)BB * RR * CC)  // 13,107,200

#define KSPLIT 32
#define KCHUNK (CC / KSPLIT)  // 64
#define KC 32

// ws layout (float offsets). Total ~8.91 MB <= proven ws capacity (9.12 MB used in r2).
#define WS_SM   ((size_t)0)                            // BB*CC = 131,072
#define WS_PART (WS_SM + (size_t)BB * CC)              // KSPLIT*BB*1024 = 2,097,152
#define WS_CNT  (WS_PART + (size_t)KSPLIT * BB * 1024) // 2 unsigned counters

#define NBLK 512

// Grid barrier: all NBLK blocks co-resident (LDS 53.4KB -> >=2 blocks/CU ->
// capacity >=512). Release: threadfence + relaxed add. Acquire: spin on
// device-scope load, then threadfence.
__device__ __forceinline__ void gridbar(unsigned* cnt) {
    __syncthreads();
    if (threadIdx.x == 0) {
        __threadfence();                 // make prior writes visible (release)
        atomicAdd(cnt, 1u);              // device-scope
        while (__hip_atomic_load(cnt, __ATOMIC_RELAXED, __HIP_MEMORY_SCOPE_AGENT) < NBLK) {
            __builtin_amdgcn_s_sleep(2);
        }
    }
    __syncthreads();
    __threadfence();                     // acquire side
}

__global__ __launch_bounds__(256) void kMega(const float* __restrict__ feats,
                                             const float* __restrict__ masks,
                                             const float* __restrict__ W1,
                                             const float* __restrict__ b1,
                                             const float* __restrict__ W2,
                                             const float* __restrict__ b2,
                                             float* out,   // S + h0 + c0
                                             float* Sm, float* part,
                                             unsigned* cnt) {
    __shared__ float shm[13352];  // union: ph1 stage[12544]+sM[800]+sMbar[8]; ph2 sW+sS
    int t = threadIdx.x;
    int bid = blockIdx.x;

    // ================= phase 1: kF body (validated r5) =================
    {
        float* stage = shm;           // [12544]
        float* sM    = shm + 12544;   // [RR*8]
        float* sMbar = shm + 13344;   // [8]
        int b = bid >> 3;
        int ctile = bid & 7;

        // per-r column sums of masks[b,r,:,:]
        float m[8] = {0.f, 0.f, 0.f, 0.f, 0.f, 0.f, 0.f, 0.f};
        if (t < RR) {
            const float* p = masks + ((size_t)b * RR + t) * 49;
#pragma unroll
            for (int i = 0; i < 7; ++i)
#pragma unroll
                for (int k = 0; k < 7; ++k) m[k] += p[i * 7 + k];
        }
#pragma unroll
        for (int k = 0; k < 8; ++k) stage[t * 8 + k] = m[k];
        if (t < RR) {
#pragma unroll
            for (int k = 0; k < 8; ++k) sM[t * 8 + k] = m[k];
        }
        __syncthreads();
        if (t < 8) {
            float s = 0.f;
            for (int r = 0; r < RR; ++r) s += stage[r * 8 + t];
            sMbar[t] = s * (1.0f / RR);
        }
        __syncthreads();  // stage reads done; sMbar/sM visible

        // stage feats[b, c0..c0+255, :, :] (50 KB) and row-sum
        const size_t base = ((size_t)b * CC + (size_t)ctile * 256) * 49;
        const float4* src = (const float4*)(feats + base);
        float4* dst = (float4*)stage;
#pragma unroll
        for (int i = 0; i < 13; ++i) {
            int idx = t + i * 256;
            if (idx < 3136) dst[idx] = src[idx];
        }
        __syncthreads();
        const float* my = stage + t * 49;
        float f0 = 0.f, f1 = 0.f, f2 = 0.f, f3 = 0.f, f4 = 0.f, f5 = 0.f, f6 = 0.f;
#pragma unroll
        for (int j = 0; j < 7; ++j) {
            f0 += my[0 * 7 + j]; f1 += my[1 * 7 + j]; f2 += my[2 * 7 + j];
            f3 += my[3 * 7 + j]; f4 += my[4 * 7 + j]; f5 += my[5 * 7 + j];
            f6 += my[6 * 7 + j];
        }
        const float inv = 1.0f / 49.0f;
        int c = ctile * 256 + t;
        float sm = f0 * sMbar[0] + f1 * sMbar[1] + f2 * sMbar[2] + f3 * sMbar[3] +
                   f4 * sMbar[4] + f5 * sMbar[5] + f6 * sMbar[6];
        Sm[(size_t)b * CC + c] = sm * inv;

        // S[b,r,c] = (1/49) dot7(M[b,r], f)
        float* Sp = out + (size_t)b * RR * CC + c;
#pragma unroll 4
        for (int r = 0; r < RR; ++r) {
            float4 m0 = *(const float4*)&sM[r * 8];
            float4 m1 = *(const float4*)&sM[r * 8 + 4];
            float v = m0.x * f0 + m0.y * f1 + m0.z * f2 + m0.w * f3 +
                      m1.x * f4 + m1.y * f5 + m1.z * f6;
            Sp[(size_t)r * CC] = v * inv;
        }
    }

    gridbar(cnt + 0);  // Sm complete & visible

    // ============ phase 2: split-K GEMM partials (validated r3 kE) ============
    if (bid < 4 * KSPLIT) {
        float (*sW)[260] = (float (*)[260])shm;          // [KC][260] = 8320 floats
        float (*sS)[68]  = (float (*)[68])(shm + 8320);  // [KC][68]  = 2176 floats
        int ht = bid & 3;   // 0..3 -> 256-h tile over concat [W1;W2]
        int ks = bid >> 2;  // 0..31
        const float* W = (ht < 2) ? W1 : W2;
        int hrow0 = (ht & 1) * 256;

        float acc[8][8];
#pragma unroll
        for (int i = 0; i < 8; ++i)
#pragma unroll
            for (int j = 0; j < 8; ++j) acc[i][j] = 0.f;

        int bg = t & 7;   // 8 groups x 8 b
        int hg = t >> 3;  // 32 groups x 8 h

        for (int sub = 0; sub < KCHUNK / KC; ++sub) {
            int c0 = ks * KCHUNK + sub * KC;
            for (int i = t; i < 256 * KC; i += 256) {
                int h = i >> 5, cc = i & 31;
                sW[cc][h] = W[(size_t)(hrow0 + h) * CC + c0 + cc];
            }
            for (int i = t; i < 64 * KC; i += 256) {
                int bb = i >> 5, cc = i & 31;
                sS[cc][bb] = Sm[(size_t)bb * CC + c0 + cc];
            }
            __syncthreads();
            for (int cc = 0; cc < KC; ++cc) {
                float4 s0 = *(const float4*)&sS[cc][bg * 8];
                float4 s1 = *(const float4*)&sS[cc][bg * 8 + 4];
                float4 w0 = *(const float4*)&sW[cc][hg * 8];
                float4 w1 = *(const float4*)&sW[cc][hg * 8 + 4];
                float fs[8] = {s0.x, s0.y, s0.z, s0.w, s1.x, s1.y, s1.z, s1.w};
                float fw[8] = {w0.x, w0.y, w0.z, w0.w, w1.x, w1.y, w1.z, w1.w};
#pragma unroll
                for (int i = 0; i < 8; ++i)
#pragma unroll
                    for (int j = 0; j < 8; ++j) acc[i][j] += fs[i] * fw[j];
            }
            __syncthreads();
        }

        int hglobal = ht * 256 + hg * 8;  // 0..1023
        float* pp = part + (size_t)ks * (BB * 1024);
#pragma unroll
        for (int i = 0; i < 8; ++i) {
            int bb = bg * 8 + i;
            float* o = pp + (size_t)bb * 1024 + hglobal;
            *(float4*)(o) = make_float4(acc[i][0], acc[i][1], acc[i][2], acc[i][3]);
            *(float4*)(o + 4) = make_float4(acc[i][4], acc[i][5], acc[i][6], acc[i][7]);
        }
    }

    gridbar(cnt + 1);  // partials complete & visible

    // ============ phase 3: reduce partials + bias (validated r3 kD2) ============
    if (bid < 256) {
        int idx = bid * 256 + t;  // 0..65535
        int b = idx >> 10;
        int h = idx & 1023;
        float s = (h < HH) ? b1[h] : b2[h - HH];
#pragma unroll
        for (int ks = 0; ks < KSPLIT; ++ks)
            s += part[(size_t)ks * (BB * 1024) + idx];
        int which = h >> 9;
        out[S_ELEMS + (size_t)which * ((size_t)BB * HH) + (size_t)b * HH + (h & 511)] = s;
    }
}

extern "C" void kernel_launch(void* const* d_in, const int* in_sizes, int n_in,
                              void* d_out, int out_size, void* d_ws, size_t ws_size,
                              hipStream_t stream) {
    const float* feats = (const float*)d_in[0];
    const float* masks = (const float*)d_in[1];
    const float* W1 = (const float*)d_in[2];
    const float* b1 = (const float*)d_in[3];
    const float* W2 = (const float*)d_in[4];
    const float* b2 = (const float*)d_in[5];
    float* out = (float*)d_out;
    float* ws = (float*)d_ws;
    float* Sm = ws + WS_SM;
    float* part = ws + WS_PART;
    unsigned* cnt = (unsigned*)(ws + WS_CNT);

    // zero the two barrier counters (ws is poisoned 0xAA; also re-zeroes between replays)
    hipMemsetAsync(cnt, 0, 2 * sizeof(unsigned), stream);

    kMega<<<NBLK, 256, 0, stream>>>(feats, masks, W1, b1, W2, b2, out, Sm, part, cnt);
}

// Round 7
// 102.905 us; speedup vs baseline: 1.7379x; 1.7379x over previous
//
#include <hip/hip_runtime.h>

#define BB 64
#define RR 100
#define CC 2048
#define HH 512

#define S_ELEMS ((size_t)BB * RR * CC)  // 13,107,200

#define KSPLIT 32
#define KCHUNK (CC / KSPLIT)  // 64
#define KC 32

// ws layout (float offsets)
#define WS_SM   ((size_t)0)                            // BB*CC = 131,072
#define WS_PART (WS_SM + (size_t)BB * CC)              // KSPLIT*BB*1024 = 2,097,152
#define WS_CNT  (WS_PART + (size_t)KSPLIT * BB * 1024) // 2 unsigned counters

#define NBLK 512

// Fence-free grid barrier. Cross-phase data (Sm, part) moves via agent-scope
// relaxed atomics (global_* sc1 -> device-coherent, NO L2 writeback/inv).
// Barrier: each thread drains its own vmem (sc1 stores now at coherent point),
// block syncs, t0 signals + spins on a device-coherent load.
__device__ __forceinline__ void gridbar(unsigned* cnt) {
    asm volatile("s_waitcnt vmcnt(0)" ::: "memory");  // my stores visible
    __syncthreads();                                  // whole block done
    if (threadIdx.x == 0) {
        __hip_atomic_fetch_add(cnt, 1u, __ATOMIC_RELAXED, __HIP_MEMORY_SCOPE_AGENT);
        while (__hip_atomic_load(cnt, __ATOMIC_RELAXED, __HIP_MEMORY_SCOPE_AGENT) < NBLK)
            __builtin_amdgcn_s_sleep(4);
    }
    __syncthreads();  // workgroup barrier (also a compiler memory barrier)
}

__device__ __forceinline__ void st_agent(float* p, float v) {
    __hip_atomic_store(p, v, __ATOMIC_RELAXED, __HIP_MEMORY_SCOPE_AGENT);
}
__device__ __forceinline__ float ld_agent(const float* p) {
    return __hip_atomic_load(p, __ATOMIC_RELAXED, __HIP_MEMORY_SCOPE_AGENT);
}

__global__ __launch_bounds__(256) void kMega(const float* __restrict__ feats,
                                             const float* __restrict__ masks,
                                             const float* __restrict__ W1,
                                             const float* __restrict__ b1,
                                             const float* __restrict__ W2,
                                             const float* __restrict__ b2,
                                             float* out,   // S + h0 + c0
                                             float* Sm, float* part,
                                             unsigned* cnt) {
    __shared__ float shm[13352];  // union: ph1 stage[12544]+sM[800]+sMbar[8]; ph2 sW+sS
    int t = threadIdx.x;
    int bid = blockIdx.x;

    // ================= phase 1: kF body (validated r5/r6) =================
    {
        float* stage = shm;           // [12544]
        float* sM    = shm + 12544;   // [RR*8]
        float* sMbar = shm + 13344;   // [8]
        int b = bid >> 3;
        int ctile = bid & 7;

        // per-r column sums of masks[b,r,:,:]
        float m[8] = {0.f, 0.f, 0.f, 0.f, 0.f, 0.f, 0.f, 0.f};
        if (t < RR) {
            const float* p = masks + ((size_t)b * RR + t) * 49;
#pragma unroll
            for (int i = 0; i < 7; ++i)
#pragma unroll
                for (int k = 0; k < 7; ++k) m[k] += p[i * 7 + k];
        }
#pragma unroll
        for (int k = 0; k < 8; ++k) stage[t * 8 + k] = m[k];
        if (t < RR) {
#pragma unroll
            for (int k = 0; k < 8; ++k) sM[t * 8 + k] = m[k];
        }
        __syncthreads();
        if (t < 8) {
            float s = 0.f;
            for (int r = 0; r < RR; ++r) s += stage[r * 8 + t];
            sMbar[t] = s * (1.0f / RR);
        }
        __syncthreads();  // stage reads done; sMbar/sM visible

        // stage feats[b, c0..c0+255, :, :] (50 KB) and row-sum
        const size_t base = ((size_t)b * CC + (size_t)ctile * 256) * 49;
        const float4* src = (const float4*)(feats + base);
        float4* dst = (float4*)stage;
#pragma unroll
        for (int i = 0; i < 13; ++i) {
            int idx = t + i * 256;
            if (idx < 3136) dst[idx] = src[idx];
        }
        __syncthreads();
        const float* my = stage + t * 49;
        float f0 = 0.f, f1 = 0.f, f2 = 0.f, f3 = 0.f, f4 = 0.f, f5 = 0.f, f6 = 0.f;
#pragma unroll
        for (int j = 0; j < 7; ++j) {
            f0 += my[0 * 7 + j]; f1 += my[1 * 7 + j]; f2 += my[2 * 7 + j];
            f3 += my[3 * 7 + j]; f4 += my[4 * 7 + j]; f5 += my[5 * 7 + j];
            f6 += my[6 * 7 + j];
        }
        const float inv = 1.0f / 49.0f;
        int c = ctile * 256 + t;
        float sm = f0 * sMbar[0] + f1 * sMbar[1] + f2 * sMbar[2] + f3 * sMbar[3] +
                   f4 * sMbar[4] + f5 * sMbar[5] + f6 * sMbar[6];
        st_agent(&Sm[(size_t)b * CC + c], sm * inv);  // device-coherent

        // S[b,r,c] = (1/49) dot7(M[b,r], f) — normal stores (host-visible at kernel end)
        float* Sp = out + (size_t)b * RR * CC + c;
#pragma unroll 4
        for (int r = 0; r < RR; ++r) {
            float4 m0 = *(const float4*)&sM[r * 8];
            float4 m1 = *(const float4*)&sM[r * 8 + 4];
            float v = m0.x * f0 + m0.y * f1 + m0.z * f2 + m0.w * f3 +
                      m1.x * f4 + m1.y * f5 + m1.z * f6;
            Sp[(size_t)r * CC] = v * inv;
        }
    }

    gridbar(cnt + 0);  // Sm complete & visible

    // ============ phase 2: split-K GEMM partials (validated r3/r6) ============
    if (bid < 4 * KSPLIT) {
        float (*sW)[260] = (float (*)[260])shm;          // [KC][260]
        float (*sS)[68]  = (float (*)[68])(shm + 8320);  // [KC][68]
        int ht = bid & 3;   // 0..3 -> 256-h tile over concat [W1;W2]
        int ks = bid >> 2;  // 0..31
        const float* W = (ht < 2) ? W1 : W2;
        int hrow0 = (ht & 1) * 256;

        float acc[8][8];
#pragma unroll
        for (int i = 0; i < 8; ++i)
#pragma unroll
            for (int j = 0; j < 8; ++j) acc[i][j] = 0.f;

        int bg = t & 7;   // 8 groups x 8 b
        int hg = t >> 3;  // 32 groups x 8 h

        for (int sub = 0; sub < KCHUNK / KC; ++sub) {
            int c0 = ks * KCHUNK + sub * KC;
            for (int i = t; i < 256 * KC; i += 256) {
                int h = i >> 5, cc = i & 31;
                sW[cc][h] = W[(size_t)(hrow0 + h) * CC + c0 + cc];
            }
            for (int i = t; i < 64 * KC; i += 256) {
                int bb = i >> 5, cc = i & 31;
                sS[cc][bb] = ld_agent(&Sm[(size_t)bb * CC + c0 + cc]);  // coherent
            }
            __syncthreads();
            for (int cc = 0; cc < KC; ++cc) {
                float4 s0 = *(const float4*)&sS[cc][bg * 8];
                float4 s1 = *(const float4*)&sS[cc][bg * 8 + 4];
                float4 w0 = *(const float4*)&sW[cc][hg * 8];
                float4 w1 = *(const float4*)&sW[cc][hg * 8 + 4];
                float fs[8] = {s0.x, s0.y, s0.z, s0.w, s1.x, s1.y, s1.z, s1.w};
                float fw[8] = {w0.x, w0.y, w0.z, w0.w, w1.x, w1.y, w1.z, w1.w};
#pragma unroll
                for (int i = 0; i < 8; ++i)
#pragma unroll
                    for (int j = 0; j < 8; ++j) acc[i][j] += fs[i] * fw[j];
            }
            __syncthreads();
        }

        int hglobal = ht * 256 + hg * 8;  // 0..1023
        float* pp = part + (size_t)ks * (BB * 1024);
#pragma unroll
        for (int i = 0; i < 8; ++i) {
            int bb = bg * 8 + i;
            float* o = pp + (size_t)bb * 1024 + hglobal;
#pragma unroll
            for (int j = 0; j < 8; ++j) st_agent(&o[j], acc[i][j]);  // coherent
        }
    }

    gridbar(cnt + 1);  // partials complete & visible

    // ============ phase 3: reduce partials + bias (validated r3/r6) ============
    if (bid < 256) {
        int idx = bid * 256 + t;  // 0..65535
        int b = idx >> 10;
        int h = idx & 1023;
        float s = (h < HH) ? b1[h] : b2[h - HH];
#pragma unroll
        for (int ks = 0; ks < KSPLIT; ++ks)
            s += ld_agent(&part[(size_t)ks * (BB * 1024) + idx]);  // coherent
        int which = h >> 9;
        out[S_ELEMS + (size_t)which * ((size_t)BB * HH) + (size_t)b * HH + (h & 511)] = s;
    }
}

extern "C" void kernel_launch(void* const* d_in, const int* in_sizes, int n_in,
                              void* d_out, int out_size, void* d_ws, size_t ws_size,
                              hipStream_t stream) {
    const float* feats = (const float*)d_in[0];
    const float* masks = (const float*)d_in[1];
    const float* W1 = (const float*)d_in[2];
    const float* b1 = (const float*)d_in[3];
    const float* W2 = (const float*)d_in[4];
    const float* b2 = (const float*)d_in[5];
    float* out = (float*)d_out;
    float* ws = (float*)d_ws;
    float* Sm = ws + WS_SM;
    float* part = ws + WS_PART;
    unsigned* cnt = (unsigned*)(ws + WS_CNT);

    // zero the two barrier counters each call (replay-deterministic)
    hipMemsetAsync(cnt, 0, 2 * sizeof(unsigned), stream);

    kMega<<<NBLK, 256, 0, stream>>>(feats, masks, W1, b1, W2, b2, out, Sm, part, cnt);
}

// Round 8
// 61.705 us; speedup vs baseline: 2.8982x; 1.6677x over previous
//
#include <hip/hip_runtime.h>

#define BB 64
#define RR 100
#define CC 2048
#define HH 512

#define S_ELEMS ((size_t)BB * RR * CC)  // 13,107,200

#define KSPLIT 32
#define KCHUNK (CC / KSPLIT)  // 64
#define KC 32

// ws layout (float offsets)
#define WS_SM   ((size_t)0)                            // BB*CC = 131,072
#define WS_PART (WS_SM + (size_t)BB * CC)              // KSPLIT*1024*64 = 2,097,152
#define WS_SYNC (WS_PART + (size_t)KSPLIT * 1024 * 64) // slots1[512] slots2[512] flag1 flag2

#define NBLK 512

__device__ __forceinline__ void st_agent(float* p, float v) {
    __hip_atomic_store(p, v, __ATOMIC_RELAXED, __HIP_MEMORY_SCOPE_AGENT);
}
__device__ __forceinline__ float ld_agent(const float* p) {
    return __hip_atomic_load(p, __ATOMIC_RELAXED, __HIP_MEMORY_SCOPE_AGENT);
}

// RMW-free grid barrier: per-block slot store (parallel, no serialization),
// block-0 wave-0 sweeps slots (8 coherent loads/lane), sets release flag.
// Waiters poll flag with backoff. All 512 blocks co-resident (proven r6/r7).
__device__ __forceinline__ void gridbar2(unsigned* slots, unsigned* flag) {
    asm volatile("s_waitcnt vmcnt(0)" ::: "memory");  // my sc1 stores at coherent point
    __syncthreads();                                  // whole block done
    const int t = threadIdx.x;
    if (t == 0)
        __hip_atomic_store(&slots[blockIdx.x], 1u, __ATOMIC_RELAXED, __HIP_MEMORY_SCOPE_AGENT);
    if (blockIdx.x == 0) {
        if (t < 64) {
            for (;;) {
                unsigned a0 = __hip_atomic_load(&slots[t * 8 + 0], __ATOMIC_RELAXED, __HIP_MEMORY_SCOPE_AGENT);
                unsigned a1 = __hip_atomic_load(&slots[t * 8 + 1], __ATOMIC_RELAXED, __HIP_MEMORY_SCOPE_AGENT);
                unsigned a2 = __hip_atomic_load(&slots[t * 8 + 2], __ATOMIC_RELAXED, __HIP_MEMORY_SCOPE_AGENT);
                unsigned a3 = __hip_atomic_load(&slots[t * 8 + 3], __ATOMIC_RELAXED, __HIP_MEMORY_SCOPE_AGENT);
                unsigned a4 = __hip_atomic_load(&slots[t * 8 + 4], __ATOMIC_RELAXED, __HIP_MEMORY_SCOPE_AGENT);
                unsigned a5 = __hip_atomic_load(&slots[t * 8 + 5], __ATOMIC_RELAXED, __HIP_MEMORY_SCOPE_AGENT);
                unsigned a6 = __hip_atomic_load(&slots[t * 8 + 6], __ATOMIC_RELAXED, __HIP_MEMORY_SCOPE_AGENT);
                unsigned a7 = __hip_atomic_load(&slots[t * 8 + 7], __ATOMIC_RELAXED, __HIP_MEMORY_SCOPE_AGENT);
                if (__all((a0 & a1 & a2 & a3 & a4 & a5 & a6 & a7) == 1u)) break;
                __builtin_amdgcn_s_sleep(8);
            }
            if (t == 0)
                __hip_atomic_store(flag, 1u, __ATOMIC_RELAXED, __HIP_MEMORY_SCOPE_AGENT);
        }
    } else if (t == 0) {
        while (__hip_atomic_load(flag, __ATOMIC_RELAXED, __HIP_MEMORY_SCOPE_AGENT) == 0u)
            __builtin_amdgcn_s_sleep(32);
    }
    __syncthreads();
}

__global__ __launch_bounds__(256) void kMega(const float* __restrict__ feats,
                                             const float* __restrict__ masks,
                                             const float* __restrict__ W1,
                                             const float* __restrict__ b1,
                                             const float* __restrict__ W2,
                                             const float* __restrict__ b2,
                                             float* out,   // S + h0 + c0
                                             float* Sm, float* part,
                                             unsigned* sync) {
    __shared__ float shm[13352];  // union: ph1 stage[12544]+sM[800]+sMbar[8]; ph2 sW+sS
    int t = threadIdx.x;
    int bid = blockIdx.x;

    // ================= phase 1: kF body (validated r5/r6/r7) =================
    {
        float* stage = shm;           // [12544]
        float* sM    = shm + 12544;   // [RR*8]
        float* sMbar = shm + 13344;   // [8]
        int b = bid >> 3;
        int ctile = bid & 7;

        float m[8] = {0.f, 0.f, 0.f, 0.f, 0.f, 0.f, 0.f, 0.f};
        if (t < RR) {
            const float* p = masks + ((size_t)b * RR + t) * 49;
#pragma unroll
            for (int i = 0; i < 7; ++i)
#pragma unroll
                for (int k = 0; k < 7; ++k) m[k] += p[i * 7 + k];
        }
#pragma unroll
        for (int k = 0; k < 8; ++k) stage[t * 8 + k] = m[k];
        if (t < RR) {
#pragma unroll
            for (int k = 0; k < 8; ++k) sM[t * 8 + k] = m[k];
        }
        __syncthreads();
        if (t < 8) {
            float s = 0.f;
            for (int r = 0; r < RR; ++r) s += stage[r * 8 + t];
            sMbar[t] = s * (1.0f / RR);
        }
        __syncthreads();

        const size_t base = ((size_t)b * CC + (size_t)ctile * 256) * 49;
        const float4* src = (const float4*)(feats + base);
        float4* dst = (float4*)stage;
#pragma unroll
        for (int i = 0; i < 13; ++i) {
            int idx = t + i * 256;
            if (idx < 3136) dst[idx] = src[idx];
        }
        __syncthreads();
        const float* my = stage + t * 49;
        float f0 = 0.f, f1 = 0.f, f2 = 0.f, f3 = 0.f, f4 = 0.f, f5 = 0.f, f6 = 0.f;
#pragma unroll
        for (int j = 0; j < 7; ++j) {
            f0 += my[0 * 7 + j]; f1 += my[1 * 7 + j]; f2 += my[2 * 7 + j];
            f3 += my[3 * 7 + j]; f4 += my[4 * 7 + j]; f5 += my[5 * 7 + j];
            f6 += my[6 * 7 + j];
        }
        const float inv = 1.0f / 49.0f;
        int c = ctile * 256 + t;
        float sm = f0 * sMbar[0] + f1 * sMbar[1] + f2 * sMbar[2] + f3 * sMbar[3] +
                   f4 * sMbar[4] + f5 * sMbar[5] + f6 * sMbar[6];
        st_agent(&Sm[(size_t)b * CC + c], sm * inv);  // device-coherent, coalesced

        float* Sp = out + (size_t)b * RR * CC + c;
#pragma unroll 4
        for (int r = 0; r < RR; ++r) {
            float4 m0 = *(const float4*)&sM[r * 8];
            float4 m1 = *(const float4*)&sM[r * 8 + 4];
            float v = m0.x * f0 + m0.y * f1 + m0.z * f2 + m0.w * f3 +
                      m1.x * f4 + m1.y * f5 + m1.z * f6;
            Sp[(size_t)r * CC] = v * inv;
        }
    }

    gridbar2(sync, sync + 1024);  // Sm complete & visible

    // ============ phase 2: split-K GEMM partials (validated r3/r6/r7) ============
    if (bid < 4 * KSPLIT) {
        float (*sW)[260] = (float (*)[260])shm;          // [KC][260]
        float (*sS)[68]  = (float (*)[68])(shm + 8320);  // [KC][68]
        int ht = bid & 3;   // 0..3 -> 256-h tile over concat [W1;W2]
        int ks = bid >> 2;  // 0..31
        const float* W = (ht < 2) ? W1 : W2;
        int hrow0 = (ht & 1) * 256;

        float acc[8][8];
#pragma unroll
        for (int i = 0; i < 8; ++i)
#pragma unroll
            for (int j = 0; j < 8; ++j) acc[i][j] = 0.f;

        int bg = t & 7;   // 8 groups x 8 b
        int hg = t >> 3;  // 32 groups x 8 h

        for (int sub = 0; sub < KCHUNK / KC; ++sub) {
            int c0 = ks * KCHUNK + sub * KC;
            for (int i = t; i < 256 * KC; i += 256) {
                int h = i >> 5, cc = i & 31;
                sW[cc][h] = W[(size_t)(hrow0 + h) * CC + c0 + cc];
            }
            for (int i = t; i < 64 * KC; i += 256) {
                int bb = i >> 5, cc = i & 31;
                sS[cc][bb] = ld_agent(&Sm[(size_t)bb * CC + c0 + cc]);
            }
            __syncthreads();
            for (int cc = 0; cc < KC; ++cc) {
                float4 s0 = *(const float4*)&sS[cc][bg * 8];
                float4 s1 = *(const float4*)&sS[cc][bg * 8 + 4];
                float4 w0 = *(const float4*)&sW[cc][hg * 8];
                float4 w1 = *(const float4*)&sW[cc][hg * 8 + 4];
                float fs[8] = {s0.x, s0.y, s0.z, s0.w, s1.x, s1.y, s1.z, s1.w};
                float fw[8] = {w0.x, w0.y, w0.z, w0.w, w1.x, w1.y, w1.z, w1.w};
#pragma unroll
                for (int i = 0; i < 8; ++i)
#pragma unroll
                    for (int j = 0; j < 8; ++j) acc[i][j] += fs[i] * fw[j];
            }
            __syncthreads();
        }

        // part layout [ks][h(1024)][b(64)] -> sc1 stores ~2 lanes/64B line
        int hbase = ht * 256 + hg * 8;
        float* pp = part + (size_t)ks * (1024 * 64);
#pragma unroll
        for (int j = 0; j < 8; ++j) {
            float* row = pp + (size_t)(hbase + j) * 64 + bg * 8;
#pragma unroll
            for (int i = 0; i < 8; ++i) st_agent(&row[i], acc[i][j]);
        }
    }

    gridbar2(sync + 512, sync + 1025);  // partials complete & visible

    // ============ phase 3: reduce partials + bias (validated r3/r6/r7) ============
    if (bid < 256) {
        int idx = bid * 256 + t;  // 0..65535 over [h(1024)][b(64)]
        int h = idx >> 6;
        int b = idx & 63;
        float s = (h < HH) ? b1[h] : b2[h - HH];
#pragma unroll
        for (int ks = 0; ks < KSPLIT; ++ks)
            s += ld_agent(&part[(size_t)ks * (1024 * 64) + idx]);  // line-dense reads
        int which = h >> 9;
        out[S_ELEMS + (size_t)which * ((size_t)BB * HH) + (size_t)b * HH + (h & 511)] = s;
    }
}

extern "C" void kernel_launch(void* const* d_in, const int* in_sizes, int n_in,
                              void* d_out, int out_size, void* d_ws, size_t ws_size,
                              hipStream_t stream) {
    const float* feats = (const float*)d_in[0];
    const float* masks = (const float*)d_in[1];
    const float* W1 = (const float*)d_in[2];
    const float* b1 = (const float*)d_in[3];
    const float* W2 = (const float*)d_in[4];
    const float* b2 = (const float*)d_in[5];
    float* out = (float*)d_out;
    float* ws = (float*)d_ws;
    float* Sm = ws + WS_SM;
    float* part = ws + WS_PART;
    unsigned* sync = (unsigned*)(ws + WS_SYNC);

    // zero slots1[512], slots2[512], flag1, flag2 each call (replay-deterministic)
    hipMemsetAsync(sync, 0, 1026 * sizeof(unsigned), stream);

    kMega<<<NBLK, 256, 0, stream>>>(feats, masks, W1, b1, W2, b2, out, Sm, part, sync);
}

// Round 9
// 52.175 us; speedup vs baseline: 3.4276x; 1.1826x over previous
//
#include <hip/hip_runtime.h>

#define BB 64
#define RR 100
#define CC 2048
#define HH 512

#define S_ELEMS ((size_t)BB * RR * CC)  // 13,107,200

#define KSPLIT 32
#define KCHUNK (CC / KSPLIT)  // 64
#define KC 32
#define NBLK 512

// ws layout (float offsets)
#define WS_SM   ((size_t)0)                            // BB*CC = 131,072
#define WS_PART (WS_SM + (size_t)BB * CC)              // KSPLIT*1024*64 = 2,097,152
#define WS_SYNC (WS_PART + (size_t)KSPLIT * 1024 * 64) // slots1[512] slots2[128]

__device__ __forceinline__ void sta(float* p, float v) {
    __hip_atomic_store(p, v, __ATOMIC_RELAXED, __HIP_MEMORY_SCOPE_AGENT);
}
__device__ __forceinline__ float lda(const float* p) {
    return __hip_atomic_load(p, __ATOMIC_RELAXED, __HIP_MEMORY_SCOPE_AGENT);
}
__device__ __forceinline__ void sta_u(unsigned* p, unsigned v) {
    __hip_atomic_store(p, v, __ATOMIC_RELAXED, __HIP_MEMORY_SCOPE_AGENT);
}
__device__ __forceinline__ unsigned lda_u(const unsigned* p) {
    return __hip_atomic_load(p, __ATOMIC_RELAXED, __HIP_MEMORY_SCOPE_AGENT);
}
union F2U { float2 f; unsigned long long u; };
__device__ __forceinline__ void sta_x2(float* p, float a, float b) {
    F2U x; x.f = make_float2(a, b);
    __hip_atomic_store((unsigned long long*)p, x.u, __ATOMIC_RELAXED, __HIP_MEMORY_SCOPE_AGENT);
}

// signal: drain this wave's vmem (sc1 stores at coherent point), sync block, mark slot
__device__ __forceinline__ void bar_signal(unsigned* slot) {
    asm volatile("s_waitcnt vmcnt(0)" ::: "memory");
    __syncthreads();
    if (threadIdx.x == 0) sta_u(slot, 1u);
}

__global__ __launch_bounds__(256) void kMega(const float* __restrict__ feats,
                                             const float* __restrict__ masks,
                                             const float* __restrict__ W1,
                                             const float* __restrict__ b1,
                                             const float* __restrict__ W2,
                                             const float* __restrict__ b2,
                                             float* out,   // S + h0 + c0
                                             float* Sm, float* part,
                                             unsigned* slots1, unsigned* slots2) {
    __shared__ float shm[13352];  // ph1: stage+sM+sMbar; ph2: sW+sS then buf[128][66]; ph3: s4
    int t = threadIdx.x;
    int bid = blockIdx.x;

    // ================= phase 1: kF body (validated r5-r8) =================
    {
        float* stage = shm;           // [12544]
        float* sM    = shm + 12544;   // [RR*8]
        float* sMbar = shm + 13344;   // [8]
        int b = bid >> 3;
        int ctile = bid & 7;

        float m[8] = {0.f, 0.f, 0.f, 0.f, 0.f, 0.f, 0.f, 0.f};
        if (t < RR) {
            const float* p = masks + ((size_t)b * RR + t) * 49;
#pragma unroll
            for (int i = 0; i < 7; ++i)
#pragma unroll
                for (int k = 0; k < 7; ++k) m[k] += p[i * 7 + k];
        }
#pragma unroll
        for (int k = 0; k < 8; ++k) stage[t * 8 + k] = m[k];
        if (t < RR) {
#pragma unroll
            for (int k = 0; k < 8; ++k) sM[t * 8 + k] = m[k];
        }
        __syncthreads();
        if (t < 8) {
            float s = 0.f;
            for (int r = 0; r < RR; ++r) s += stage[r * 8 + t];
            sMbar[t] = s * (1.0f / RR);
        }
        __syncthreads();

        const size_t base = ((size_t)b * CC + (size_t)ctile * 256) * 49;
        const float4* src = (const float4*)(feats + base);
        float4* dst = (float4*)stage;
#pragma unroll
        for (int i = 0; i < 13; ++i) {
            int idx = t + i * 256;
            if (idx < 3136) dst[idx] = src[idx];
        }
        __syncthreads();
        const float* my = stage + t * 49;
        float f0 = 0.f, f1 = 0.f, f2 = 0.f, f3 = 0.f, f4 = 0.f, f5 = 0.f, f6 = 0.f;
#pragma unroll
        for (int j = 0; j < 7; ++j) {
            f0 += my[0 * 7 + j]; f1 += my[1 * 7 + j]; f2 += my[2 * 7 + j];
            f3 += my[3 * 7 + j]; f4 += my[4 * 7 + j]; f5 += my[5 * 7 + j];
            f6 += my[6 * 7 + j];
        }
        const float inv = 1.0f / 49.0f;
        int c = ctile * 256 + t;
        float sm = f0 * sMbar[0] + f1 * sMbar[1] + f2 * sMbar[2] + f3 * sMbar[3] +
                   f4 * sMbar[4] + f5 * sMbar[5] + f6 * sMbar[6];
        sta(&Sm[(size_t)b * CC + c], sm * inv);  // device-coherent, lane-dense

        float* Sp = out + (size_t)b * RR * CC + c;
#pragma unroll 4
        for (int r = 0; r < RR; ++r) {
            float4 m0 = *(const float4*)&sM[r * 8];
            float4 m1 = *(const float4*)&sM[r * 8 + 4];
            float v = m0.x * f0 + m0.y * f1 + m0.z * f2 + m0.w * f3 +
                      m1.x * f4 + m1.y * f5 + m1.z * f6;
            Sp[(size_t)r * CC] = v * inv;
        }
    }

    bar_signal(&slots1[bid]);   // bid = b*8 + ctile
    if (bid >= 256) return;     // phase-1-only blocks free their CU

    // ============ phase 2: split-K GEMM (K-loop validated r3/r6-r8) ============
    if (bid < 4 * KSPLIT) {
        int ht = bid & 3;   // 256-h tile over concat [W1;W2]
        int ks = bid >> 2;  // 0..31
        int ct = ks >> 2;   // the single ctile this K-chunk needs

        // wait only for the 64 producers of ctile ct: slots1[b*8+ct]
        if (t < 64) {
            const unsigned* s = slots1 + ct + t * 8;
            while (lda_u(s) == 0u) __builtin_amdgcn_s_sleep(2);
        }
        __syncthreads();

        float (*sW)[260] = (float (*)[260])shm;          // [KC][260]
        float (*sS)[68]  = (float (*)[68])(shm + 8320);  // [KC][68]
        const float* W = (ht < 2) ? W1 : W2;
        int hrow0 = (ht & 1) * 256;

        float acc[8][8];
#pragma unroll
        for (int i = 0; i < 8; ++i)
#pragma unroll
            for (int j = 0; j < 8; ++j) acc[i][j] = 0.f;

        int bg = t & 7;   // 8 groups x 8 b
        int hg = t >> 3;  // 32 groups x 8 h

        for (int sub = 0; sub < KCHUNK / KC; ++sub) {
            int c0 = ks * KCHUNK + sub * KC;
            for (int i = t; i < 256 * KC; i += 256) {
                int h = i >> 5, cc = i & 31;
                sW[cc][h] = W[(size_t)(hrow0 + h) * CC + c0 + cc];
            }
            for (int i = t; i < 64 * KC; i += 256) {
                int bb = i >> 5, cc = i & 31;
                sS[cc][bb] = lda(&Sm[(size_t)bb * CC + c0 + cc]);
            }
            __syncthreads();
            for (int cc = 0; cc < KC; ++cc) {
                float4 s0 = *(const float4*)&sS[cc][bg * 8];
                float4 s1 = *(const float4*)&sS[cc][bg * 8 + 4];
                float4 w0 = *(const float4*)&sW[cc][hg * 8];
                float4 w1 = *(const float4*)&sW[cc][hg * 8 + 4];
                float fs[8] = {s0.x, s0.y, s0.z, s0.w, s1.x, s1.y, s1.z, s1.w};
                float fw[8] = {w0.x, w0.y, w0.z, w0.w, w1.x, w1.y, w1.z, w1.w};
#pragma unroll
                for (int i = 0; i < 8; ++i)
#pragma unroll
                    for (int j = 0; j < 8; ++j) acc[i][j] += fs[i] * fw[j];
            }
            __syncthreads();
        }

        // transpose epilogue -> part[ks][h][b], lane-dense 8B coherent stores
        float* buf = shm;  // [128][66] = 8448 floats
        for (int ch = 0; ch < 2; ++ch) {
            __syncthreads();  // buf free / previous chunk's readers done
            if ((hg >> 4) == ch) {
                int hl = (hg & 15) * 8;
#pragma unroll
                for (int j = 0; j < 8; ++j)
#pragma unroll
                    for (int i = 0; i < 8; ++i)
                        buf[(hl + j) * 66 + bg * 8 + i] = acc[i][j];
            }
            __syncthreads();
            float* dst = part + (size_t)ks * (1024 * 64) + ((size_t)ht * 256 + ch * 128) * 64;
            for (int f = t; f < 4096; f += 256) {   // 4096 float2 = 8192 floats
                int hl = f >> 5;
                int c0 = (f & 31) * 2;
                sta_x2(dst + f * 2, buf[hl * 66 + c0], buf[hl * 66 + c0 + 1]);
            }
        }

        bar_signal(&slots2[bid]);  // bid = ks*4 + ht
    }

    // ============ phase 3: reduce partials + bias (math validated r3/r6-r8) ============
    {
        int htp = bid >> 6;  // which 256-h tile my h-range lives in
        // wait only for the 32 GEMM blocks of this ht: slots2[k*4 + htp]
        if (t < 32) {
            const unsigned* s = slots2 + htp + t * 4;
            while (lda_u(s) == 0u) __builtin_amdgcn_s_sleep(2);
        }
        __syncthreads();

        int hl = t >> 6;         // 0..3
        int b = t & 63;
        int h = bid * 4 + hl;    // 0..1023
        float s = (h < HH) ? b1[h] : b2[h - HH];
#pragma unroll
        for (int ks = 0; ks < KSPLIT; ++ks)
            s += lda(&part[(size_t)ks * (1024 * 64) + (size_t)h * 64 + b]);  // lane-dense

        // small LDS bounce so out-writes are h-contiguous per 4 lanes
        __syncthreads();  // GEMM blocks reused shm; ensure free
        float* s4 = shm;  // [4][65]
        s4[hl * 65 + b] = s;
        __syncthreads();
        int b2 = t >> 2, h2l = t & 3;
        int h2 = bid * 4 + h2l;
        int which = h2 >> 9;
        out[S_ELEMS + (size_t)which * ((size_t)BB * HH) + (size_t)b2 * HH + (h2 & 511)] =
            s4[h2l * 65 + b2];
    }
}

extern "C" void kernel_launch(void* const* d_in, const int* in_sizes, int n_in,
                              void* d_out, int out_size, void* d_ws, size_t ws_size,
                              hipStream_t stream) {
    const float* feats = (const float*)d_in[0];
    const float* masks = (const float*)d_in[1];
    const float* W1 = (const float*)d_in[2];
    const float* b1 = (const float*)d_in[3];
    const float* W2 = (const float*)d_in[4];
    const float* b2 = (const float*)d_in[5];
    float* out = (float*)d_out;
    float* ws = (float*)d_ws;
    float* Sm = ws + WS_SM;
    float* part = ws + WS_PART;
    unsigned* slots1 = (unsigned*)(ws + WS_SYNC);
    unsigned* slots2 = slots1 + 512;

    // zero slots1[512]+slots2[128] each call (replay-deterministic)
    hipMemsetAsync(slots1, 0, 640 * sizeof(unsigned), stream);

    kMega<<<NBLK, 256, 0, stream>>>(feats, masks, W1, b1, W2, b2, out, Sm, part,
                                    slots1, slots2);
}